// Round 1
// baseline (962.977 us; speedup 1.0000x reference)
//
#include <hip/hip_runtime.h>
#include <hip/hip_bf16.h>
#include <stdint.h>

#define DEV static __device__ __forceinline__

typedef __bf16 bf16_t;
typedef __bf16 bf16x8 __attribute__((ext_vector_type(8)));
typedef __bf16 bf16x4 __attribute__((ext_vector_type(4)));
typedef float  f32x4  __attribute__((ext_vector_type(4)));

// Problem constants
// H=32 q heads, KV=8 kv heads, D=128, HID=4096, S=4, L=1024, N=4096

DEV void gload_lds16(const void* g, void* l) {
  __builtin_amdgcn_global_load_lds(
      (__attribute__((address_space(1))) void*)(uintptr_t)(g),
      (__attribute__((address_space(3))) void*)(uintptr_t)(l),
      16, 0, 0);
}

// ---------------- pack/convert kernels ----------------
// A,B: [rows][4096] f32  ->  dst [rows][8192] bf16 with dst[r][0:4096]=A[r], dst[r][4096:]=B[r]
__global__ void k_pack_pair(const float* __restrict__ A, const float* __restrict__ B,
                            bf16_t* __restrict__ dst, int rows) {
  size_t n4 = (size_t)rows * 1024;  // float4 per source
  size_t stride = (size_t)gridDim.x * blockDim.x;
  for (size_t i = (size_t)blockIdx.x * blockDim.x + threadIdx.x; i < n4; i += stride) {
    size_t r = i >> 10, c4 = i & 1023;
    float4 va = ((const float4*)A)[i];
    float4 vb = ((const float4*)B)[i];
    bf16x4 oa = { (bf16_t)va.x, (bf16_t)va.y, (bf16_t)va.z, (bf16_t)va.w };
    bf16x4 ob = { (bf16_t)vb.x, (bf16_t)vb.y, (bf16_t)vb.z, (bf16_t)vb.w };
    ((bf16x4*)dst)[r * 2048 + c4]        = oa;
    ((bf16x4*)dst)[r * 2048 + 1024 + c4] = ob;
  }
}

__global__ void k_convert(const float* __restrict__ A, bf16_t* __restrict__ dst, size_t n4) {
  size_t stride = (size_t)gridDim.x * blockDim.x;
  for (size_t i = (size_t)blockIdx.x * blockDim.x + threadIdx.x; i < n4; i += stride) {
    float4 v = ((const float4*)A)[i];
    bf16x4 o = { (bf16_t)v.x, (bf16_t)v.y, (bf16_t)v.z, (bf16_t)v.w };
    ((bf16x4*)dst)[i] = o;
  }
}

// ---------------- bf16 GEMM: C[M][N] = A[M][K] * B[N][K]^T (m97 structure) ----------------
__global__ __launch_bounds__(256, 2) void k_gemm_bt(
    const bf16_t* __restrict__ A, const bf16_t* __restrict__ B,
    float* __restrict__ C, int M, int N, int K) {
  __shared__ __align__(16) bf16_t As[128 * 32];
  __shared__ __align__(16) bf16_t Bs[128 * 32];
  const int tid = threadIdx.x;
  const int lane = tid & 63, wid = tid >> 6;
  const int l15 = lane & 15, lhi = lane >> 4;
  const int wr = wid >> 1, wc = wid & 1;
  const int bn = blockIdx.x, bm = blockIdx.y;
  const bf16_t* Ab = A + (size_t)bm * 128 * K;
  const bf16_t* Bb = B + (size_t)bn * 128 * K;
  const int ow0 = wid * 1024, ow1 = ow0 + 4096;     // wave-uniform LDS bases
  const int o0 = ow0 + lane * 16, o1 = ow1 + lane * 16;
  const int r0 = o0 >> 6, cb0 = o0 & 63;
  const int r1 = o1 >> 6, cb1 = o1 & 63;
  const char* Ag0 = (const char*)(Ab + (size_t)r0 * K) + cb0;
  const char* Ag1 = (const char*)(Ab + (size_t)r1 * K) + cb1;
  const char* Bg0 = (const char*)(Bb + (size_t)r0 * K) + cb0;
  const char* Bg1 = (const char*)(Bb + (size_t)r1 * K) + cb1;
  f32x4 acc[4][4] = {};
  for (int kt = 0; kt < K; kt += 32) {
    const size_t kb = (size_t)kt * 2;
    gload_lds16(Ag0 + kb, (char*)As + ow0);
    gload_lds16(Ag1 + kb, (char*)As + ow1);
    gload_lds16(Bg0 + kb, (char*)Bs + ow0);
    gload_lds16(Bg1 + kb, (char*)Bs + ow1);
    __syncthreads();
    bf16x8 af[4], bfr[4];
#pragma unroll
    for (int m = 0; m < 4; m++)
      af[m] = *(const bf16x8*)(As + (wr * 64 + m * 16 + l15) * 32 + 8 * lhi);
#pragma unroll
    for (int n = 0; n < 4; n++)
      bfr[n] = *(const bf16x8*)(Bs + (wc * 64 + n * 16 + l15) * 32 + 8 * lhi);
#pragma unroll
    for (int m = 0; m < 4; m++)
#pragma unroll
      for (int n = 0; n < 4; n++)
        acc[m][n] = __builtin_amdgcn_mfma_f32_16x16x32_bf16(af[m], bfr[n], acc[m][n], 0, 0, 0);
    __syncthreads();
  }
#pragma unroll
  for (int m = 0; m < 4; m++) {
    const int gr0 = bm * 128 + wr * 64 + m * 16 + 4 * lhi;
#pragma unroll
    for (int n = 0; n < 4; n++) {
      const int gc = bn * 128 + wc * 64 + n * 16 + l15;
#pragma unroll
      for (int i = 0; i < 4; i++)
        C[(size_t)(gr0 + i) * N + gc] = acc[m][n][i];
    }
  }
}

// ---------------- RMSNorm + RoPE + bf16 pack of Q/K/V ----------------
// one wave per (token, slot): slot 0-31 q heads, 32-39 k heads, 40-47 v heads
__global__ __launch_bounds__(256) void k_norm_rope(
    const float* __restrict__ qkv, const int* __restrict__ pos,
    const float* __restrict__ qw, const float* __restrict__ kw,
    bf16_t* __restrict__ Q, bf16_t* __restrict__ Kk, bf16_t* __restrict__ V) {
  const int w = blockIdx.x * 4 + (threadIdx.x >> 6);
  const int lane = threadIdx.x & 63;
  const int n = w / 48, slot = w % 48;
  const float* row = qkv + (size_t)n * 6144;
  if (slot >= 40) {
    const int h2 = slot - 40;
    float x0 = row[5120 + h2 * 128 + lane];
    float x1 = row[5120 + h2 * 128 + lane + 64];
    bf16_t* dst = V + ((size_t)n * 8 + h2) * 128;
    dst[lane] = (bf16_t)x0;
    dst[lane + 64] = (bf16_t)x1;
    return;
  }
  const bool isq = slot < 32;
  const int h = isq ? slot : slot - 32;
  const int coff = isq ? h * 128 : 4096 + h * 128;
  float x0 = row[coff + lane], x1 = row[coff + lane + 64];
  float ss = x0 * x0 + x1 * x1;
#pragma unroll
  for (int m = 32; m; m >>= 1) ss += __shfl_xor(ss, m, 64);
  const float inv = rsqrtf(ss * (1.0f / 128.0f) + 1e-6f);
  const float* wgt = isq ? qw : kw;
  float y0 = x0 * inv * wgt[lane];
  float y1 = x1 * inv * wgt[lane + 64];
  // RoPE: inv_freq[l] = 10000^(-l/64); lane holds d=l and d=l+64 (same angle)
  const float ang = (float)pos[n] * expf((float)lane * -0.14391156608f);
  float sn, cs;
  sincosf(ang, &sn, &cs);
  float o0 = y0 * cs - y1 * sn;
  float o1 = y1 * cs + y0 * sn;
  bf16_t* dst = isq ? (Q + ((size_t)n * 32 + h) * 128) : (Kk + ((size_t)n * 8 + h) * 128);
  dst[lane] = (bf16_t)o0;
  dst[lane + 64] = (bf16_t)o1;
}

// ---------------- causal GQA flash attention ----------------
// grid: b = s*256 + h*8 + qb  (1024 blocks); 4 waves x 32 q-rows = 128-row q tile; KV tile 64
__global__ __launch_bounds__(256, 2) void k_attn(
    const bf16_t* __restrict__ Q, const bf16_t* __restrict__ Kk,
    const bf16_t* __restrict__ V, bf16_t* __restrict__ O) {
  __shared__ __align__(16) bf16_t Ks[64 * 128];   // row-major, 16B-chunk XOR swizzle (row&7)
  __shared__ __align__(16) bf16_t Vt[128 * 72];   // V^T: d-major stride 72, chunk XOR ((d>>3)&7)
  __shared__ __align__(16) bf16_t Ps[4][32 * 72]; // per-wave P bounce, stride 72
  const int b = blockIdx.x;
  const int qb = b & 7, h = (b >> 3) & 31, s = b >> 8;
  const int kvh = h >> 2;
  const int tid = threadIdx.x, lane = tid & 63, wid = tid >> 6;
  const int l15 = lane & 15, lhi = lane >> 4;

  // hoist Q fragments (A-operand: row=l15, k=kc*32+8*lhi+j)
  bf16x8 qf[2][4];
  {
    const int qrow = qb * 128 + wid * 32;
#pragma unroll
    for (int mt = 0; mt < 2; mt++) {
      const size_t base = ((size_t)(s * 1024 + qrow + mt * 16 + l15) * 32 + h) * 128;
#pragma unroll
      for (int kc = 0; kc < 4; kc++)
        qf[mt][kc] = *(const bf16x8*)(Q + base + kc * 32 + 8 * lhi);
    }
  }
  f32x4 of[2][8] = {};
  float mx[2][4], li[2][4];
#pragma unroll
  for (int mt = 0; mt < 2; mt++)
#pragma unroll
    for (int i = 0; i < 4; i++) { mx[mt][i] = -1e30f; li[mt][i] = 0.f; }

  const int ktiles = (qb + 1) * 2;
  const int vr_base = tid >> 4;          // V stage: r = c*16 + vr_base
  const int vd0 = (tid & 15) * 8;        //          d0

  for (int kt = 0; kt < ktiles; kt++) {
    const int kv0 = kt * 64;
    // stage K (global_load_lds, pre-swizzled source chunks)
#pragma unroll
    for (int c = 0; c < 4; c++) {
      const int wb = wid * 4096 + c * 1024;
      const int o = wb + lane * 16;
      const int krow = o >> 8;
      const int ci = (o >> 4) & 15;
      const int cs = ci ^ (krow & 7);
      const char* src =
          (const char*)(Kk + ((size_t)(s * 1024 + kv0 + krow) * 8 + kvh) * 128) + cs * 16;
      gload_lds16(src, (char*)Ks + wb);
    }
    // stage V transposed (reg-staged)
#pragma unroll
    for (int c = 0; c < 4; c++) {
      const int r = c * 16 + vr_base;
      bf16x8 v = *(const bf16x8*)(V + ((size_t)(s * 1024 + kv0 + r) * 8 + kvh) * 128 + vd0);
#pragma unroll
      for (int j = 0; j < 8; j++) {
        const int d = vd0 + j;
        const int cc = (r >> 3) ^ ((d >> 3) & 7);
        Vt[d * 72 + cc * 8 + (r & 7)] = v[j];
      }
    }
    __syncthreads();

    // QK^T : S[32 q][64 kv]
    f32x4 sf[2][4] = {};
#pragma unroll
    for (int kc = 0; kc < 4; kc++) {
      bf16x8 kf[4];
#pragma unroll
      for (int n = 0; n < 4; n++) {
        const int krow = n * 16 + l15;
        const int ci = (kc * 4 + lhi) ^ (krow & 7);
        kf[n] = *(const bf16x8*)(Ks + krow * 128 + ci * 8);
      }
#pragma unroll
      for (int mt = 0; mt < 2; mt++)
#pragma unroll
        for (int n = 0; n < 4; n++)
          sf[mt][n] = __builtin_amdgcn_mfma_f32_16x16x32_bf16(qf[mt][kc], kf[n], sf[mt][n], 0, 0, 0);
    }

    // online softmax (D-layout: col=l15 -> kv, row=4*lhi+i -> q)
    const bool masked = (kt >= 2 * qb);
    const float scale = 0.08838834764831845f;  // 1/sqrt(128)
    float pv[2][4][4];
#pragma unroll
    for (int mt = 0; mt < 2; mt++) {
#pragma unroll
      for (int i = 0; i < 4; i++) {
        float rm = -1e30f;
#pragma unroll
        for (int n = 0; n < 4; n++) {
          float sv = sf[mt][n][i] * scale;
          if (masked) {
            const int kvg = kv0 + n * 16 + l15;
            const int qg = qb * 128 + wid * 32 + mt * 16 + 4 * lhi + i;
            if (kvg > qg) sv = -1e30f;
          }
          pv[mt][n][i] = sv;
          rm = fmaxf(rm, sv);
        }
#pragma unroll
        for (int mm = 1; mm < 16; mm <<= 1) rm = fmaxf(rm, __shfl_xor(rm, mm, 64));
        const float nm = fmaxf(mx[mt][i], rm);
        float ts = 0.f;
#pragma unroll
        for (int n = 0; n < 4; n++) {
          float e = __expf(pv[mt][n][i] - nm);
          pv[mt][n][i] = e;
          ts += e;
        }
#pragma unroll
        for (int mm = 1; mm < 16; mm <<= 1) ts += __shfl_xor(ts, mm, 64);
        const float al = __expf(mx[mt][i] - nm);
        li[mt][i] = li[mt][i] * al + ts;
        mx[mt][i] = nm;
#pragma unroll
        for (int n = 0; n < 8; n++) of[mt][n][i] *= al;
      }
    }

    // P -> per-wave LDS (bf16), re-read in A-operand layout
    bf16_t* myP = &Ps[wid][0];
#pragma unroll
    for (int mt = 0; mt < 2; mt++)
#pragma unroll
      for (int n = 0; n < 4; n++)
#pragma unroll
        for (int i = 0; i < 4; i++)
          myP[(mt * 16 + 4 * lhi + i) * 72 + n * 16 + l15] = (bf16_t)pv[mt][n][i];

    // PV : O[32 q][128 d] += P[32][64] * V[64][128]
#pragma unroll
    for (int kc = 0; kc < 2; kc++) {
      bf16x8 pf[2];
#pragma unroll
      for (int mt = 0; mt < 2; mt++)
        pf[mt] = *(const bf16x8*)(myP + (mt * 16 + l15) * 72 + kc * 32 + 8 * lhi);
#pragma unroll
      for (int n = 0; n < 8; n++) {
        const int d = n * 16 + l15;
        const int cc = (kc * 4 + lhi) ^ ((d >> 3) & 7);
        bf16x8 vf = *(const bf16x8*)(Vt + d * 72 + cc * 8);
#pragma unroll
        for (int mt = 0; mt < 2; mt++)
          of[mt][n] = __builtin_amdgcn_mfma_f32_16x16x32_bf16(pf[mt], vf, of[mt][n], 0, 0, 0);
      }
    }
    __syncthreads();
  }

  // epilogue: normalize + store bf16 O[token][h*128+d]
#pragma unroll
  for (int mt = 0; mt < 2; mt++) {
#pragma unroll
    for (int i = 0; i < 4; i++) {
      const float invl = 1.0f / li[mt][i];
      const int tokrow = qb * 128 + wid * 32 + mt * 16 + 4 * lhi + i;
      bf16_t* dst = O + (size_t)(s * 1024 + tokrow) * 4096 + h * 128;
#pragma unroll
      for (int n = 0; n < 8; n++)
        dst[n * 16 + l15] = (bf16_t)(of[mt][n][i] * invl);
    }
  }
}

// ---------------- launch ----------------
extern "C" void kernel_launch(void* const* d_in, const int* in_sizes, int n_in,
                              void* d_out, int out_size, void* d_ws, size_t ws_size,
                              hipStream_t stream) {
  const float* hidden = (const float*)d_in[0];
  const float* mu     = (const float*)d_in[1];
  const int*   pos    = (const int*)d_in[2];
  const float* Wq  = (const float*)d_in[3];
  const float* Wk  = (const float*)d_in[4];
  const float* Wv  = (const float*)d_in[5];
  const float* Wo  = (const float*)d_in[6];
  const float* Wmq = (const float*)d_in[7];
  const float* Wmk = (const float*)d_in[8];
  const float* Wmv = (const float*)d_in[9];
  const float* qw  = (const float*)d_in[10];
  const float* kw  = (const float*)d_in[11];
  float* out = (float*)d_out;
  char* ws = (char*)d_ws;

  if (ws_size < 301989888u) return;  // need 288 MiB

  bf16_t* Wqkv = (bf16_t*)(ws);                    // [6144][8192] bf16 = 100663296 B
  bf16_t* Wob  = (bf16_t*)(ws + 100663296);        // [4096][4096] bf16 = 33554432 B
  bf16_t* Xb   = (bf16_t*)(ws + 134217728);        // [4096][8192] bf16 = 67108864 B
  bf16_t* Qb   = (bf16_t*)(ws + 134217728);        // aliases Xb (dead after GEMM1)
  bf16_t* Kb   = (bf16_t*)(ws + 167772160);
  bf16_t* Vb   = (bf16_t*)(ws + 176160768);
  float*  qkv  = (float*)(ws + 201326592);         // [4096][6144] f32 = 100663296 B
  bf16_t* Ob   = (bf16_t*)(ws + 201326592);        // aliases qkv (dead after norm/rope)

  k_pack_pair<<<2048, 256, 0, stream>>>(hidden, mu, Xb, 4096);
  k_pack_pair<<<2048, 256, 0, stream>>>(Wq, Wmq, Wqkv, 4096);
  k_pack_pair<<<1024, 256, 0, stream>>>(Wk, Wmk, Wqkv + (size_t)4096 * 8192, 1024);
  k_pack_pair<<<1024, 256, 0, stream>>>(Wv, Wmv, Wqkv + (size_t)5120 * 8192, 1024);
  k_convert<<<2048, 256, 0, stream>>>(Wo, Wob, (size_t)4096 * 4096 / 4);

  k_gemm_bt<<<dim3(48, 32), 256, 0, stream>>>(Xb, Wqkv, qkv, 4096, 6144, 8192);
  k_norm_rope<<<49152, 256, 0, stream>>>(qkv, pos, qw, kw, Qb, Kb, Vb);
  k_attn<<<1024, 256, 0, stream>>>(Qb, Kb, Vb, Ob);
  k_gemm_bt<<<dim3(32, 32), 256, 0, stream>>>(Ob, Wob, out, 4096, 4096, 4096);
}